// Round 1
// baseline (3242.076 us; speedup 1.0000x reference)
//
#include <hip/hip_runtime.h>

#define DIMV 70
#define NEL 6
#define BATCH 8

// ---------------------------------------------------------------------------
// zero helper (float4 granular)
__global__ __launch_bounds__(256) void k_zero(float* __restrict__ p, int n4) {
  int i = blockIdx.x * 256 + threadIdx.x;
  if (i < n4) ((float4*)p)[i] = make_float4(0.f, 0.f, 0.f, 0.f);
}

// ---------------------------------------------------------------------------
// Gaussian blob scatter. One block per (b,e) channel. Exploits ~1e-4 sparsity.
// Reference: G[a,i] = exp(-((a-35)-i)^2 / (2 sigma^2)); truncate at R=16
// (exp(-32) ~ 1e-14, far below the 1.9e-3 output threshold).
__global__ __launch_bounds__(256) void k_blur(const float* __restrict__ x,
                                              const float* __restrict__ sigma,
                                              float* __restrict__ cube) {
  const int CH = DIMV * DIMV * DIMV;  // 343000
  int b = blockIdx.x / NEL, e = blockIdx.x % NEL;
  size_t base = (size_t)(b * NEL + e) * CH;
  __shared__ int s_cnt;
  __shared__ int s_atoms[512];
  __shared__ float wa[33], wp[33], wq[33];
  int tid = threadIdx.x;
  if (tid == 0) s_cnt = 0;
  __syncthreads();
  // scan for atoms (float4 loads; 343000 = 4*85750)
  const float4* x4 = (const float4*)(x + base);
  for (int j = tid; j < CH / 4; j += 256) {
    float4 v = x4[j];
    if (v.x != 0.f) { int p = atomicAdd(&s_cnt, 1); if (p < 512) s_atoms[p] = 4 * j; }
    if (v.y != 0.f) { int p = atomicAdd(&s_cnt, 1); if (p < 512) s_atoms[p] = 4 * j + 1; }
    if (v.z != 0.f) { int p = atomicAdd(&s_cnt, 1); if (p < 512) s_atoms[p] = 4 * j + 2; }
    if (v.w != 0.f) { int p = atomicAdd(&s_cnt, 1); if (p < 512) s_atoms[p] = 4 * j + 3; }
  }
  __syncthreads();
  int n = min(s_cnt, 512);
  float sg = sigma[e];
  float inv2s2 = 1.f / (2.f * sg * sg);
  const int R = 16;
  for (int t = 0; t < n; ++t) {
    int idx = s_atoms[t];
    int z0 = idx % DIMV;
    int y0 = (idx / DIMV) % DIMV;
    int x0 = idx / (DIMV * DIMV);
    int a0 = max(0, x0 + 35 - R), a1 = min(DIMV - 1, x0 + 35 + R);
    int p0 = max(0, y0 + 35 - R), p1 = min(DIMV - 1, y0 + 35 + R);
    int q0 = max(0, z0 + 35 - R), q1 = min(DIMV - 1, z0 + 35 + R);
    int na = a1 - a0 + 1, npp = p1 - p0 + 1, nq = q1 - q0 + 1;
    if (na <= 0 || npp <= 0 || nq <= 0) continue;  // uniform branch (shared data)
    if (tid < 33) {
      int da = a0 + tid - 35 - x0;
      int dp = p0 + tid - 35 - y0;
      int dq = q0 + tid - 35 - z0;
      wa[tid] = (tid < na) ? expf(-(float)(da * da) * inv2s2) : 0.f;
      wp[tid] = (tid < npp) ? expf(-(float)(dp * dp) * inv2s2) : 0.f;
      wq[tid] = (tid < nq) ? expf(-(float)(dq * dq) * inv2s2) : 0.f;
    }
    __syncthreads();
    int tot = na * npp * nq;
    for (int v = tid; v < tot; v += 256) {
      int q = v % nq;
      int r = v / nq;
      int p = r % npp;
      int a = r / npp;
      cube[base + (size_t)((a0 + a) * 4900 + (p0 + p) * 70 + (q0 + q))] += wa[a] * wp[p] * wq[q];
    }
    __syncthreads();
  }
}

// ---------------------------------------------------------------------------
// Generic 3x3x3 VALID conv + 2x2x2 max-pool + ReLU, one thread per pooled
// output. Register-blocks the 4x4x4 input patch per channel: 64 loads ->
// 216 FMA (3.4 MAC/load). Zero-patch skip (helps conv1: cube is exactly 0
// outside blobs; conv2+ are dense because of the +0.01 bias before ReLU).
__global__ __launch_bounds__(256) void k_conv_pool_relu(
    const float* __restrict__ in, const float* __restrict__ wt,
    const float* __restrict__ bias, float* __restrict__ out,
    int CIN, int COUT, int DIN, int DP, int total) {
  int gid = blockIdx.x * 256 + threadIdx.x;
  if (gid >= total) return;
  int pw = gid % DP; int t = gid / DP;
  int ph = t % DP;   t /= DP;
  int pd = t % DP;   t /= DP;
  int o  = t % COUT;
  int b  = t / COUT;
  int S = DIN * DIN;
  const float* inb = in + (size_t)b * CIN * DIN * S;
  const float* ip = inb + (size_t)(2 * pd) * S + (2 * ph) * DIN + (2 * pw);
  const float* wbase = wt + (size_t)o * CIN * 27;
  float acc[2][2][2] = {{{0.f, 0.f}, {0.f, 0.f}}, {{0.f, 0.f}, {0.f, 0.f}}};
  for (int c = 0; c < CIN; ++c) {
    const float* icp = ip + (size_t)c * DIN * S;
    float r[4][4][4];
    unsigned nz = 0u;
#pragma unroll
    for (int dz = 0; dz < 4; ++dz)
#pragma unroll
      for (int dy = 0; dy < 4; ++dy)
#pragma unroll
        for (int dx = 0; dx < 4; ++dx) {
          float v = icp[dz * S + dy * DIN + dx];
          r[dz][dy][dx] = v;
          nz |= __float_as_uint(v);
        }
    if (!(nz & 0x7fffffffu)) continue;  // whole patch zero -> no contribution
    float w[27];
    const float* wc = wbase + c * 27;
#pragma unroll
    for (int k = 0; k < 27; ++k) w[k] = wc[k];
#pragma unroll
    for (int kd = 0; kd < 3; ++kd)
#pragma unroll
      for (int kh = 0; kh < 3; ++kh)
#pragma unroll
        for (int kw = 0; kw < 3; ++kw) {
          float wv = w[(kd * 3 + kh) * 3 + kw];
#pragma unroll
          for (int dd = 0; dd < 2; ++dd)
#pragma unroll
            for (int hh = 0; hh < 2; ++hh)
#pragma unroll
              for (int ww = 0; ww < 2; ++ww)
                acc[dd][hh][ww] = fmaf(r[kd + dd][kh + hh][kw + ww], wv, acc[dd][hh][ww]);
        }
  }
  float m = acc[0][0][0];
  m = fmaxf(m, acc[0][0][1]);
  m = fmaxf(m, acc[0][1][0]);
  m = fmaxf(m, acc[0][1][1]);
  m = fmaxf(m, acc[1][0][0]);
  m = fmaxf(m, acc[1][0][1]);
  m = fmaxf(m, acc[1][1][0]);
  m = fmaxf(m, acc[1][1][1]);
  out[gid] = fmaxf(m + bias[o], 0.f);
}

// ---------------------------------------------------------------------------
// FC: one 64-lane wave per output element, coalesced K reads, shfl reduce.
__global__ __launch_bounds__(64) void k_fc(const float* __restrict__ v,
                                           const float* __restrict__ W,
                                           const float* __restrict__ bias,
                                           float* __restrict__ y,
                                           int K, int N, int do_relu) {
  int blk = blockIdx.x;  // b*N + o
  int b = blk / N, o = blk % N;
  int lane = threadIdx.x;
  const float* vp = v + (size_t)b * K;
  const float* wp = W + (size_t)o * K;
  float acc = 0.f;
  for (int k = lane; k < K; k += 64) acc = fmaf(vp[k], wp[k], acc);
#pragma unroll
  for (int off = 32; off > 0; off >>= 1) acc += __shfl_xor(acc, off);
  if (lane == 0) {
    float r = acc + bias[o];
    y[blk] = do_relu ? fmaxf(r, 0.f) : r;
  }
}

// ---------------------------------------------------------------------------
extern "C" void kernel_launch(void* const* d_in, const int* in_sizes, int n_in,
                              void* d_out, int out_size, void* d_ws, size_t ws_size,
                              hipStream_t stream) {
  const float* x   = (const float*)d_in[0];
  const float* sig = (const float*)d_in[1];
  const float* w1  = (const float*)d_in[2];
  const float* b1  = (const float*)d_in[3];
  const float* w2  = (const float*)d_in[4];
  const float* b2  = (const float*)d_in[5];
  const float* w3  = (const float*)d_in[6];
  const float* b3  = (const float*)d_in[7];
  const float* w4  = (const float*)d_in[8];
  const float* b4  = (const float*)d_in[9];
  const float* fw1 = (const float*)d_in[10];
  const float* fb1 = (const float*)d_in[11];
  const float* fw2 = (const float*)d_in[12];
  const float* fb2 = (const float*)d_in[13];

  char* ws = (char*)d_ws;
  // cube: [8,6,70^3] f32 = 65,856,000 B @ 0
  // h1:   [8,32,34^3] f32 = 40,247,296 B @ 65,856,000   (peak use ~106.1 MB)
  // h2:   [8,64,16^3] reuses cube slab @ 0
  // h3:   [8,128,7^3] reuses h1 slab   @ 65,856,000
  // h4:   [8,256,2^3] @ 0 (h2 dead)
  // y1:   [8,1024]    @ 1 MiB
  float* cube = (float*)(ws + 0);
  float* h1   = (float*)(ws + 65856000);
  float* h2   = (float*)(ws + 0);
  float* h3   = (float*)(ws + 65856000);
  float* h4   = (float*)(ws + 0);
  float* y1   = (float*)(ws + (1u << 20));

  const int cube_f4 = (BATCH * NEL * DIMV * DIMV * DIMV) / 4;  // 4,116,000
  k_zero<<<(cube_f4 + 255) / 256, 256, 0, stream>>>(cube, cube_f4);
  k_blur<<<BATCH * NEL, 256, 0, stream>>>(x, sig, cube);

  int tot1 = BATCH * 32 * 34 * 34 * 34;
  k_conv_pool_relu<<<(tot1 + 255) / 256, 256, 0, stream>>>(cube, w1, b1, h1, 6, 32, 70, 34, tot1);
  int tot2 = BATCH * 64 * 16 * 16 * 16;
  k_conv_pool_relu<<<(tot2 + 255) / 256, 256, 0, stream>>>(h1, w2, b2, h2, 32, 64, 34, 16, tot2);
  int tot3 = BATCH * 128 * 7 * 7 * 7;
  k_conv_pool_relu<<<(tot3 + 255) / 256, 256, 0, stream>>>(h2, w3, b3, h3, 64, 128, 16, 7, tot3);
  int tot4 = BATCH * 256 * 2 * 2 * 2;
  k_conv_pool_relu<<<(tot4 + 255) / 256, 256, 0, stream>>>(h3, w4, b4, h4, 128, 256, 7, 2, tot4);

  k_fc<<<BATCH * 1024, 64, 0, stream>>>(h4, fw1, fb1, y1, 2048, 1024, 1);
  k_fc<<<BATCH * 29, 64, 0, stream>>>(y1, fw2, fb2, (float*)d_out, 1024, 29, 0);
}

// Round 5
// 1903.949 us; speedup vs baseline: 1.7028x; 1.7028x over previous
//
#include <hip/hip_runtime.h>
#include <hip/hip_bf16.h>

#define DIMV 70
#define NEL 6
#define BATCH 8

typedef unsigned short u16;
typedef unsigned int u32;
typedef __bf16 bf16x8 __attribute__((ext_vector_type(8)));
typedef short short8v __attribute__((ext_vector_type(8)));
typedef float f32x4 __attribute__((ext_vector_type(4)));

__device__ __forceinline__ u16 f2bf(float f) {
  __hip_bfloat16 h = __float2bfloat16(f);
  return __builtin_bit_cast(u16, h);
}
__device__ __forceinline__ float bf2f(u16 u) {
  unsigned int x = ((unsigned int)u) << 16;
  return __builtin_bit_cast(float, x);
}

// ---------------------------------------------------------------------------
__global__ __launch_bounds__(256) void k_zero(float* __restrict__ p, int n4) {
  int i = blockIdx.x * 256 + threadIdx.x;
  if (i < n4) ((float4*)p)[i] = make_float4(0.f, 0.f, 0.f, 0.f);
}

// ---------------------------------------------------------------------------
// Gaussian blob scatter (proven exact vs reference in round 1's pass).
__global__ __launch_bounds__(256) void k_blur(const float* __restrict__ x,
                                              const float* __restrict__ sigma,
                                              float* __restrict__ cube, int b0) {
  const int CH = DIMV * DIMV * DIMV;
  int bl = blockIdx.x / NEL, e = blockIdx.x % NEL;
  size_t base_in = (size_t)((b0 + bl) * NEL + e) * CH;
  size_t base_out = (size_t)(bl * NEL + e) * CH;
  __shared__ int s_cnt;
  __shared__ int s_atoms[512];
  __shared__ float wa[33], wp[33], wq[33];
  int tid = threadIdx.x;
  if (tid == 0) s_cnt = 0;
  __syncthreads();
  const float4* x4 = (const float4*)(x + base_in);
  for (int j = tid; j < CH / 4; j += 256) {
    float4 v = x4[j];
    if (v.x != 0.f) { int p = atomicAdd(&s_cnt, 1); if (p < 512) s_atoms[p] = 4 * j; }
    if (v.y != 0.f) { int p = atomicAdd(&s_cnt, 1); if (p < 512) s_atoms[p] = 4 * j + 1; }
    if (v.z != 0.f) { int p = atomicAdd(&s_cnt, 1); if (p < 512) s_atoms[p] = 4 * j + 2; }
    if (v.w != 0.f) { int p = atomicAdd(&s_cnt, 1); if (p < 512) s_atoms[p] = 4 * j + 3; }
  }
  __syncthreads();
  int n = min(s_cnt, 512);
  float sg = sigma[e];
  float inv2s2 = 1.f / (2.f * sg * sg);
  const int R = 16;
  for (int t = 0; t < n; ++t) {
    int idx = s_atoms[t];
    int z0 = idx % DIMV;
    int y0 = (idx / DIMV) % DIMV;
    int x0 = idx / (DIMV * DIMV);
    int a0 = max(0, x0 + 35 - R), a1 = min(DIMV - 1, x0 + 35 + R);
    int p0 = max(0, y0 + 35 - R), p1 = min(DIMV - 1, y0 + 35 + R);
    int q0 = max(0, z0 + 35 - R), q1 = min(DIMV - 1, z0 + 35 + R);
    int na = a1 - a0 + 1, npp = p1 - p0 + 1, nq = q1 - q0 + 1;
    if (na <= 0 || npp <= 0 || nq <= 0) continue;
    if (tid < 33) {
      int da = a0 + tid - 35 - x0;
      int dp = p0 + tid - 35 - y0;
      int dq = q0 + tid - 35 - z0;
      wa[tid] = (tid < na) ? expf(-(float)(da * da) * inv2s2) : 0.f;
      wp[tid] = (tid < npp) ? expf(-(float)(dp * dp) * inv2s2) : 0.f;
      wq[tid] = (tid < nq) ? expf(-(float)(dq * dq) * inv2s2) : 0.f;
    }
    __syncthreads();
    int tot = na * npp * nq;
    for (int v = tid; v < tot; v += 256) {
      int q = v % nq;
      int r = v / nq;
      int p = r % npp;
      int a = r / npp;
      cube[base_out + (size_t)((a0 + a) * 4900 + (p0 + p) * 70 + (q0 + q))] += wa[a] * wp[p] * wq[q];
    }
    __syncthreads();
  }
}

// ---------------------------------------------------------------------------
// Weight packs: 3-term split. Slot s of logical channel c (slot index 3c+s):
//   s=0: w_hi (pairs x_hi), s=1: w_hi (pairs x_lo), s=2: w_lo (pairs x_hi).
__global__ __launch_bounds__(256) void k_pack_c1(const float* __restrict__ w,
                                                 u16* __restrict__ A) {
  int idx = blockIdx.x * 256 + threadIdx.x;
  if (idx >= 32 * 896) return;
  int o = idx / 896, kp = idx % 896;
  int cb = kp / 448, r = kp % 448;
  int kk = r >> 5, j32 = r & 31;
  int g = j32 >> 3, e = j32 & 7;
  int off = 2 * kk + (g >> 1);
  int G = 16 * cb + 8 * (g & 1) + e;
  u16 val = 0;
  if (off < 27 && G < 18) {
    int c = G / 3, s = G % 3;
    float wv = w[(o * 6 + c) * 27 + off];
    u16 hi = f2bf(wv);
    val = (s == 2) ? f2bf(wv - bf2f(hi)) : hi;
  }
  A[idx] = val;
}
__global__ __launch_bounds__(256) void k_pack_c32(const float* __restrict__ w,
                                                  u16* __restrict__ A,
                                                  int CINL, int COUT) {
  int K2 = CINL * 81;  // (3*CINL/32)*27*32
  int idx = blockIdx.x * 256 + threadIdx.x;
  if (idx >= COUT * K2) return;
  int o = idx / K2, kp = idx % K2;
  int cb = kp / 864, r = kp % 864;
  int off = r >> 5, j = r & 31;
  int G = cb * 32 + j;
  int c = G / 3, s = G % 3;
  float wv = w[(o * CINL + c) * 27 + off];
  u16 hi = f2bf(wv);
  A[idx] = (s == 2) ? f2bf(wv - bf2f(hi)) : hi;
}

// ---------------------------------------------------------------------------
// Implicit-GEMM conv3x3x3 + fused 2x2x2 max-pool + bias + ReLU, MFMA 16x16x32,
// 3-term bf16 split (~fp32 grade). NO LDS swizzle: each MFMA's 64 lanes read
// (line fixed, consecutive x, c-chunks) = 1024 consecutive bytes -> bank-
// uniform; staging writes are consecutive too. (Rounds 2-4 failed on a
// non-bijective xx-based XOR swizzle: DIN not power-of-2 => write collisions.)
template <int CINL, int COUT, int DIN, int CC, int WAVES, int MREP, int XT>
__global__ __launch_bounds__(WAVES * 64) void k_conv_mfma(
    const u16* __restrict__ Apack, const float* __restrict__ in,
    const float* __restrict__ bias, float* __restrict__ out, int b0) {
  constexpr int DOUT = DIN - 2;
  constexpr int DP = DOUT / 2;
  constexpr int SL = 3 * CINL;                  // split slots
  constexpr int CCH = (SL + CC - 1) / CC;       // slot-chunks
  constexpr int CHUNKS = (CC == 16) ? 14 : 27;  // 32-K chunks per slot-chunk
  constexpr int K2 = CCH * CHUNKS * 32;
  __shared__ __align__(16) u16 T[16 * DIN * CC];

  const int tid = threadIdx.x;
  const int wave = tid >> 6, lane = tid & 63;
  const int n = lane & 15, g = lane >> 4;
  const int py = blockIdx.x % DP, pz = blockIdx.x / DP;
  const int bl = blockIdx.y;
  const int bG = blockIdx.y + b0;

  f32x4 acc[MREP][4][XT] = {};

  for (int cb = 0; cb < CCH; ++cb) {
    if (cb) __syncthreads();
    // conv1's second chunk has only 2 live slots (A is 0 elsewhere; stale LDS
    // in dead slots multiplies zero weights)
    const int CCnz = (CC == 16 && cb == 1) ? 2 : CC;
    const int E = 16 * DIN * CCnz;
    for (int i = tid; i < E; i += WAVES * 64) {
      int xx = i % DIN;
      int t2 = i / DIN;
      int j = t2 % CCnz;
      int line = t2 / CCnz;
      int z = 2 * pz + (line >> 2), y = 2 * py + (line & 3);
      int G = cb * CC + j;
      u16 val = 0;
      if (G < SL) {
        int c = G / 3, s = G % 3;
        float v = in[(((size_t)(bl * CINL + c) * DIN + z) * DIN + y) * DIN + xx];
        u16 hi = f2bf(v);
        val = (s == 1) ? f2bf(v - bf2f(hi)) : hi;
      }
      T[(line * DIN + xx) * CC + j] = val;
    }
    __syncthreads();
    for (int kk = 0; kk < CHUNKS; ++kk) {
      int kbase = (cb * CHUNKS + kk) * 32;
      bf16x8 afr[MREP];
#pragma unroll
      for (int mr = 0; mr < MREP; ++mr) {
        int mtile = wave + WAVES * mr;
        const u16* ap = Apack + (size_t)(mtile * 16 + n) * K2 + kbase + 8 * g;
        afr[mr] = __builtin_bit_cast(bf16x8, *(const short8v*)ap);
      }
      int off, c8;
      if (CC == 16) { off = min(2 * kk + (g >> 1), 26); c8 = 8 * (g & 1); }
      else          { off = kk;                          c8 = 8 * g; }
      int dz = off / 9, dy = (off / 3) % 3, dx = off % 3;
#pragma unroll
      for (int rc = 0; rc < 4; ++rc) {
        int line = ((rc >> 1) + dz) * 4 + ((rc & 1) + dy);
#pragma unroll
        for (int nt = 0; nt < XT; ++nt) {
          int x_in = nt * 16 + n + dx;
          if (x_in > DIN - 1) x_in = DIN - 1;  // padded lanes -> discarded outputs
          bf16x8 bfr = __builtin_bit_cast(
              bf16x8, *(const short8v*)&T[(line * DIN + x_in) * CC + c8]);
#pragma unroll
          for (int mr = 0; mr < MREP; ++mr)
            acc[mr][rc][nt] =
                __builtin_amdgcn_mfma_f32_16x16x32_bf16(afr[mr], bfr, acc[mr][rc][nt], 0, 0, 0);
        }
      }
    }
  }
  // epilogue: pool rows in-reg, x-pairs via shfl, bias, relu, f32 store
#pragma unroll
  for (int mr = 0; mr < MREP; ++mr) {
    int mtile = wave + WAVES * mr;
#pragma unroll
    for (int nt = 0; nt < XT; ++nt) {
#pragma unroll
      for (int r = 0; r < 4; ++r) {
        float v = fmaxf(fmaxf(acc[mr][0][nt][r], acc[mr][1][nt][r]),
                        fmaxf(acc[mr][2][nt][r], acc[mr][3][nt][r]));
        float v2 = fmaxf(v, __shfl_xor(v, 1));
        int o = mtile * 16 + 4 * g + r;
        int px = (nt * 16 + n) >> 1;
        if (!(n & 1) && px < DP) {
          float rv = fmaxf(v2 + bias[o], 0.f);
          out[((((size_t)bG * COUT + o) * DP + pz) * DP + py) * DP + px] = rv;
        }
      }
    }
  }
}

// ---------------------------------------------------------------------------
__global__ __launch_bounds__(64) void k_fc1(const float* __restrict__ v,
                                            const float* __restrict__ W,
                                            const float* __restrict__ bias,
                                            float* __restrict__ y) {
  int o = blockIdx.x;
  int lane = threadIdx.x;
  float acc[8] = {};
  for (int k = lane; k < 2048; k += 64) {
    float wv = W[o * 2048 + k];
#pragma unroll
    for (int bb = 0; bb < 8; ++bb)
      acc[bb] = fmaf(v[bb * 2048 + k], wv, acc[bb]);
  }
#pragma unroll
  for (int off = 32; off; off >>= 1)
#pragma unroll
    for (int bb = 0; bb < 8; ++bb) acc[bb] += __shfl_xor(acc[bb], off);
  if (lane == 0) {
    float bo = bias[o];
#pragma unroll
    for (int bb = 0; bb < 8; ++bb) y[bb * 1024 + o] = fmaxf(acc[bb] + bo, 0.f);
  }
}

__global__ __launch_bounds__(64) void k_fc2(const float* __restrict__ v,
                                            const float* __restrict__ W,
                                            const float* __restrict__ bias,
                                            float* __restrict__ y) {
  int o = blockIdx.x;
  int lane = threadIdx.x;
  float acc[8] = {};
  for (int k = lane; k < 1024; k += 64) {
    float wv = W[o * 1024 + k];
#pragma unroll
    for (int bb = 0; bb < 8; ++bb)
      acc[bb] = fmaf(v[bb * 1024 + k], wv, acc[bb]);
  }
#pragma unroll
  for (int off = 32; off; off >>= 1)
#pragma unroll
    for (int bb = 0; bb < 8; ++bb) acc[bb] += __shfl_xor(acc[bb], off);
  if (lane == 0) {
    float bo = bias[o];
#pragma unroll
    for (int bb = 0; bb < 8; ++bb) y[bb * 29 + o] = acc[bb] + bo;
  }
}

// ---------------------------------------------------------------------------
extern "C" void kernel_launch(void* const* d_in, const int* in_sizes, int n_in,
                              void* d_out, int out_size, void* d_ws, size_t ws_size,
                              hipStream_t stream) {
  const float* x   = (const float*)d_in[0];
  const float* sig = (const float*)d_in[1];
  const float* w1  = (const float*)d_in[2];
  const float* b1  = (const float*)d_in[3];
  const float* w2  = (const float*)d_in[4];
  const float* b2  = (const float*)d_in[5];
  const float* w3  = (const float*)d_in[6];
  const float* b3  = (const float*)d_in[7];
  const float* w4  = (const float*)d_in[8];
  const float* b4  = (const float*)d_in[9];
  const float* fw1 = (const float*)d_in[10];
  const float* fb1 = (const float*)d_in[11];
  const float* fw2 = (const float*)d_in[12];
  const float* fb2 = (const float*)d_in[13];

  char* ws = (char*)d_ws;
  // cube4 f32 (4 batches) @0: 32,928,000
  // h1 f32 @32,928,000: 40,247,296 -> ends 73,175,296
  // ap1 @73,200,000 | ap2 @73,300,000 | ap3 @73,700,000 | ap4 @75,100,000
  // h2 f32 @80,500,000 (8,388,608) | h3 f32 @89,000,000 (1,404,928)
  // h4 f32 @90,500,000 (65,536) | y1 f32 @90,600,000 (32,768)
  // peak 90.6 MB < 106.1 MB proven in round 0.
  float* cube4 = (float*)(ws + 0);
  float* h1    = (float*)(ws + 32928000);
  u16*   ap1   = (u16*)(ws + 73200000);
  u16*   ap2   = (u16*)(ws + 73300000);
  u16*   ap3   = (u16*)(ws + 73700000);
  u16*   ap4   = (u16*)(ws + 75100000);
  float* h2    = (float*)(ws + 80500000);
  float* h3    = (float*)(ws + 89000000);
  float* h4    = (float*)(ws + 90500000);
  float* y1    = (float*)(ws + 90600000);

  k_pack_c1<<<(32 * 896 + 255) / 256, 256, 0, stream>>>(w1, ap1);
  k_pack_c32<<<(64 * 2592 + 255) / 256, 256, 0, stream>>>(w2, ap2, 32, 64);
  k_pack_c32<<<(128 * 5184 + 255) / 256, 256, 0, stream>>>(w3, ap3, 64, 128);
  k_pack_c32<<<(256 * 10368 + 255) / 256, 256, 0, stream>>>(w4, ap4, 128, 256);

  const int cube4_f4 = (4 * NEL * DIMV * DIMV * DIMV) / 4;  // 2,058,000
  for (int half = 0; half < 2; ++half) {
    int b0 = 4 * half;
    k_zero<<<(cube4_f4 + 255) / 256, 256, 0, stream>>>(cube4, cube4_f4);
    k_blur<<<4 * NEL, 256, 0, stream>>>(x, sig, cube4, b0);
    k_conv_mfma<6, 32, 70, 16, 2, 1, 5>
        <<<dim3(34 * 34, 4), 128, 0, stream>>>(ap1, cube4, b1, h1, b0);
  }
  //            CINL COUT DIN CC  W  MR XT
  k_conv_mfma<32,  64, 34, 32, 4, 1, 2><<<dim3(16 * 16, 8), 256, 0, stream>>>(ap2, h1, b2, h2, 0);
  k_conv_mfma<64, 128, 16, 32, 8, 1, 1><<<dim3(7 * 7, 8),   512, 0, stream>>>(ap3, h2, b3, h3, 0);
  k_conv_mfma<128,256,  7, 32, 8, 2, 1><<<dim3(2 * 2, 8),   512, 0, stream>>>(ap4, h3, b4, h4, 0);

  k_fc1<<<1024, 64, 0, stream>>>(h4, fw1, fb1, y1);
  k_fc2<<<29, 64, 0, stream>>>(y1, fw2, fb2, (float*)d_out);
}

// Round 6
// 1179.837 us; speedup vs baseline: 2.7479x; 1.6137x over previous
//
#include <hip/hip_runtime.h>
#include <hip/hip_bf16.h>

#define DIMV 70
#define NEL 6
#define BATCH 8

typedef unsigned short u16;
typedef unsigned int u32;
typedef __bf16 bf16x8 __attribute__((ext_vector_type(8)));
typedef short short8v __attribute__((ext_vector_type(8)));
typedef float f32x4 __attribute__((ext_vector_type(4)));

__device__ __forceinline__ u16 f2bf(float f) {
  __hip_bfloat16 h = __float2bfloat16(f);
  return __builtin_bit_cast(u16, h);
}
__device__ __forceinline__ float bf2f(u16 u) {
  unsigned int x = ((unsigned int)u) << 16;
  return __builtin_bit_cast(float, x);
}

// ---------------------------------------------------------------------------
__global__ __launch_bounds__(256) void k_zero(float* __restrict__ p, int n4) {
  int i = blockIdx.x * 256 + threadIdx.x;
  if (i < n4) ((float4*)p)[i] = make_float4(0.f, 0.f, 0.f, 0.f);
}

// ---------------------------------------------------------------------------
// Stage 1: grid-wide scan of the sparse occupancy grid -> per-channel atom
// lists. 48 channels, ~34 atoms each (cap 512). Coalesced float4 reads.
__global__ __launch_bounds__(256) void k_scan(const float* __restrict__ x,
                                              int* __restrict__ cnt,
                                              int* __restrict__ lists) {
  const int N4 = (BATCH * NEL * DIMV * DIMV * DIMV) / 4;  // 4,116,000
  int i = blockIdx.x * 256 + threadIdx.x;
  if (i >= N4) return;
  float4 v = ((const float4*)x)[i];
  int ch = i / 85750;                 // 343000/4 elems per channel
  int local = 4 * i - ch * 343000;
  float f[4] = {v.x, v.y, v.z, v.w};
#pragma unroll
  for (int k = 0; k < 4; ++k) {
    if (f[k] != 0.f) {
      int slot = atomicAdd(&cnt[ch], 1);
      if (slot < 512) lists[ch * 512 + slot] = local + k;
    }
  }
}

// ---------------------------------------------------------------------------
// Stage 2: gather-blur. Block = (z-plane, local channel). Atoms are z-filtered
// (exp underflow -> weight 0 beyond ~16 voxels), weight tables built in LDS,
// then each thread accumulates its ~20 voxels of the 70x70 plane over atoms.
// No scatter atomics on the cube; writes each voxel exactly once.
__global__ __launch_bounds__(256) void k_gather(const int* __restrict__ cnt,
                                                const int* __restrict__ lists,
                                                const float* __restrict__ sigma,
                                                float* __restrict__ cube, int b0) {
  const int z = blockIdx.x;           // output slow dim 'a'
  const int bl = blockIdx.y / NEL;
  const int e = blockIdx.y % NEL;
  const int chG = (b0 + bl) * NEL + e;
  const int tid = threadIdx.x;
  float sg = sigma[e];
  float inv2s2 = 1.f / (2.f * sg * sg);

  __shared__ int s_n;
  __shared__ int s_idx[512];
  __shared__ float s_wz[512];
  __shared__ float s_wy[32 * 70];
  __shared__ float s_wx[32 * 70];

  if (tid == 0) s_n = 0;
  __syncthreads();
  int n = min(cnt[chG], 512);
  for (int t = tid; t < n; t += 256) {
    int idx = lists[chG * 512 + t];
    int i0 = idx / 4900;              // atom slow coord
    float d = (float)(z - 35 - i0);   // coords[z]-i0 = (z-35)-i0
    float wz = expf(-d * d * inv2s2);
    if (wz > 1e-30f) {
      int s = atomicAdd(&s_n, 1);
      s_idx[s] = idx;
      s_wz[s] = wz;
    }
  }
  __syncthreads();
  int m = s_n;

  float acc[20];
#pragma unroll
  for (int k = 0; k < 20; ++k) acc[k] = 0.f;

  for (int t0 = 0; t0 < m; t0 += 32) {
    int tn = min(32, m - t0);
    __syncthreads();
    for (int u = tid; u < tn * 70; u += 256) {
      int t = u / 70, pos = u % 70;
      int idx = s_idx[t0 + t];
      int j0 = (idx / 70) % 70, k0 = idx % 70;
      float dy = (float)(pos - 35 - j0);
      float dx = (float)(pos - 35 - k0);
      s_wy[t * 70 + pos] = s_wz[t0 + t] * expf(-dy * dy * inv2s2);
      s_wx[t * 70 + pos] = expf(-dx * dx * inv2s2);
    }
    __syncthreads();
#pragma unroll
    for (int k = 0; k < 20; ++k) {
      int v = tid + k * 256;
      if (v < 4900) {
        int y = v / 70, xx = v % 70;
        float a = 0.f;
        for (int t = 0; t < tn; ++t)
          a = fmaf(s_wy[t * 70 + y], s_wx[t * 70 + xx], a);
        acc[k] += a;
      }
    }
  }
  size_t base = ((size_t)(bl * NEL + e) * DIMV + z) * 4900;
#pragma unroll
  for (int k = 0; k < 20; ++k) {
    int v = tid + k * 256;
    if (v < 4900) cube[base + v] = acc[k];
  }
}

// ---------------------------------------------------------------------------
// Weight packs: 3-term split. Slot s of logical channel c (slot index 3c+s):
//   s=0: w_hi (pairs x_hi), s=1: w_hi (pairs x_lo), s=2: w_lo (pairs x_hi).
__global__ __launch_bounds__(256) void k_pack_c1(const float* __restrict__ w,
                                                 u16* __restrict__ A) {
  int idx = blockIdx.x * 256 + threadIdx.x;
  if (idx >= 32 * 896) return;
  int o = idx / 896, kp = idx % 896;
  int cb = kp / 448, r = kp % 448;
  int kk = r >> 5, j32 = r & 31;
  int g = j32 >> 3, e = j32 & 7;
  int off = 2 * kk + (g >> 1);
  int G = 16 * cb + 8 * (g & 1) + e;
  u16 val = 0;
  if (off < 27 && G < 18) {
    int c = G / 3, s = G % 3;
    float wv = w[(o * 6 + c) * 27 + off];
    u16 hi = f2bf(wv);
    val = (s == 2) ? f2bf(wv - bf2f(hi)) : hi;
  }
  A[idx] = val;
}
__global__ __launch_bounds__(256) void k_pack_c32(const float* __restrict__ w,
                                                  u16* __restrict__ A,
                                                  int CINL, int COUT) {
  int K2 = CINL * 81;  // (3*CINL/32)*27*32
  int idx = blockIdx.x * 256 + threadIdx.x;
  if (idx >= COUT * K2) return;
  int o = idx / K2, kp = idx % K2;
  int cb = kp / 864, r = kp % 864;
  int off = r >> 5, j = r & 31;
  int G = cb * 32 + j;
  int c = G / 3, s = G % 3;
  float wv = w[(o * CINL + c) * 27 + off];
  u16 hi = f2bf(wv);
  A[idx] = (s == 2) ? f2bf(wv - bf2f(hi)) : hi;
}

// ---------------------------------------------------------------------------
// Implicit-GEMM conv3x3x3 + fused 2x2x2 max-pool + bias + ReLU, MFMA 16x16x32,
// 3-term bf16 split (~fp32 grade). NO LDS swizzle: each MFMA's 64 lanes read
// 1024 consecutive bytes (optimal b128 service); staging writes consecutive.
template <int CINL, int COUT, int DIN, int CC, int WAVES, int MREP, int XT>
__global__ __launch_bounds__(WAVES * 64) void k_conv_mfma(
    const u16* __restrict__ Apack, const float* __restrict__ in,
    const float* __restrict__ bias, float* __restrict__ out, int b0) {
  constexpr int DOUT = DIN - 2;
  constexpr int DP = DOUT / 2;
  constexpr int SL = 3 * CINL;
  constexpr int CCH = (SL + CC - 1) / CC;
  constexpr int CHUNKS = (CC == 16) ? 14 : 27;
  constexpr int K2 = CCH * CHUNKS * 32;
  __shared__ __align__(16) u16 T[16 * DIN * CC];

  const int tid = threadIdx.x;
  const int wave = tid >> 6, lane = tid & 63;
  const int n = lane & 15, g = lane >> 4;
  const int py = blockIdx.x % DP, pz = blockIdx.x / DP;
  const int bl = blockIdx.y;
  const int bG = blockIdx.y + b0;

  f32x4 acc[MREP][4][XT] = {};

  for (int cb = 0; cb < CCH; ++cb) {
    if (cb) __syncthreads();
    const int CCnz = (CC == 16 && cb == 1) ? 2 : CC;
    const int E = 16 * DIN * CCnz;
    for (int i = tid; i < E; i += WAVES * 64) {
      int xx = i % DIN;
      int t2 = i / DIN;
      int j = t2 % CCnz;
      int line = t2 / CCnz;
      int z = 2 * pz + (line >> 2), y = 2 * py + (line & 3);
      int G = cb * CC + j;
      u16 val = 0;
      if (G < SL) {
        int c = G / 3, s = G % 3;
        float v = in[(((size_t)(bl * CINL + c) * DIN + z) * DIN + y) * DIN + xx];
        u16 hi = f2bf(v);
        val = (s == 1) ? f2bf(v - bf2f(hi)) : hi;
      }
      T[(line * DIN + xx) * CC + j] = val;
    }
    __syncthreads();
    for (int kk = 0; kk < CHUNKS; ++kk) {
      int kbase = (cb * CHUNKS + kk) * 32;
      bf16x8 afr[MREP];
#pragma unroll
      for (int mr = 0; mr < MREP; ++mr) {
        int mtile = wave + WAVES * mr;
        const u16* ap = Apack + (size_t)(mtile * 16 + n) * K2 + kbase + 8 * g;
        afr[mr] = __builtin_bit_cast(bf16x8, *(const short8v*)ap);
      }
      int off, c8;
      if (CC == 16) { off = min(2 * kk + (g >> 1), 26); c8 = 8 * (g & 1); }
      else          { off = kk;                          c8 = 8 * g; }
      int dz = off / 9, dy = (off / 3) % 3, dx = off % 3;
#pragma unroll
      for (int rc = 0; rc < 4; ++rc) {
        int line = ((rc >> 1) + dz) * 4 + ((rc & 1) + dy);
#pragma unroll
        for (int nt = 0; nt < XT; ++nt) {
          int x_in = nt * 16 + n + dx;
          if (x_in > DIN - 1) x_in = DIN - 1;
          bf16x8 bfr = __builtin_bit_cast(
              bf16x8, *(const short8v*)&T[(line * DIN + x_in) * CC + c8]);
#pragma unroll
          for (int mr = 0; mr < MREP; ++mr)
            acc[mr][rc][nt] =
                __builtin_amdgcn_mfma_f32_16x16x32_bf16(afr[mr], bfr, acc[mr][rc][nt], 0, 0, 0);
        }
      }
    }
  }
#pragma unroll
  for (int mr = 0; mr < MREP; ++mr) {
    int mtile = wave + WAVES * mr;
#pragma unroll
    for (int nt = 0; nt < XT; ++nt) {
#pragma unroll
      for (int r = 0; r < 4; ++r) {
        float v = fmaxf(fmaxf(acc[mr][0][nt][r], acc[mr][1][nt][r]),
                        fmaxf(acc[mr][2][nt][r], acc[mr][3][nt][r]));
        float v2 = fmaxf(v, __shfl_xor(v, 1));
        int o = mtile * 16 + 4 * g + r;
        int px = (nt * 16 + n) >> 1;
        if (!(n & 1) && px < DP) {
          float rv = fmaxf(v2 + bias[o], 0.f);
          out[((((size_t)bG * COUT + o) * DP + pz) * DP + py) * DP + px] = rv;
        }
      }
    }
  }
}

// ---------------------------------------------------------------------------
__global__ __launch_bounds__(64) void k_fc1(const float* __restrict__ v,
                                            const float* __restrict__ W,
                                            const float* __restrict__ bias,
                                            float* __restrict__ y) {
  int o = blockIdx.x;
  int lane = threadIdx.x;
  float acc[8] = {};
  for (int k = lane; k < 2048; k += 64) {
    float wv = W[o * 2048 + k];
#pragma unroll
    for (int bb = 0; bb < 8; ++bb)
      acc[bb] = fmaf(v[bb * 2048 + k], wv, acc[bb]);
  }
#pragma unroll
  for (int off = 32; off; off >>= 1)
#pragma unroll
    for (int bb = 0; bb < 8; ++bb) acc[bb] += __shfl_xor(acc[bb], off);
  if (lane == 0) {
    float bo = bias[o];
#pragma unroll
    for (int bb = 0; bb < 8; ++bb) y[bb * 1024 + o] = fmaxf(acc[bb] + bo, 0.f);
  }
}

__global__ __launch_bounds__(64) void k_fc2(const float* __restrict__ v,
                                            const float* __restrict__ W,
                                            const float* __restrict__ bias,
                                            float* __restrict__ y) {
  int o = blockIdx.x;
  int lane = threadIdx.x;
  float acc[8] = {};
  for (int k = lane; k < 1024; k += 64) {
    float wv = W[o * 1024 + k];
#pragma unroll
    for (int bb = 0; bb < 8; ++bb)
      acc[bb] = fmaf(v[bb * 1024 + k], wv, acc[bb]);
  }
#pragma unroll
  for (int off = 32; off; off >>= 1)
#pragma unroll
    for (int bb = 0; bb < 8; ++bb) acc[bb] += __shfl_xor(acc[bb], off);
  if (lane == 0) {
    float bo = bias[o];
#pragma unroll
    for (int bb = 0; bb < 8; ++bb) y[bb * 29 + o] = acc[bb] + bo;
  }
}

// ---------------------------------------------------------------------------
extern "C" void kernel_launch(void* const* d_in, const int* in_sizes, int n_in,
                              void* d_out, int out_size, void* d_ws, size_t ws_size,
                              hipStream_t stream) {
  const float* x   = (const float*)d_in[0];
  const float* sig = (const float*)d_in[1];
  const float* w1  = (const float*)d_in[2];
  const float* b1  = (const float*)d_in[3];
  const float* w2  = (const float*)d_in[4];
  const float* b2  = (const float*)d_in[5];
  const float* w3  = (const float*)d_in[6];
  const float* b3  = (const float*)d_in[7];
  const float* w4  = (const float*)d_in[8];
  const float* b4  = (const float*)d_in[9];
  const float* fw1 = (const float*)d_in[10];
  const float* fb1 = (const float*)d_in[11];
  const float* fw2 = (const float*)d_in[12];
  const float* fb2 = (const float*)d_in[13];

  char* ws = (char*)d_ws;
  // cube4 f32 (4 batches) @0: 32,928,000
  // h1 f32 @32,928,000: 40,247,296 -> ends 73,175,296
  // ap1 @73,200,000 | ap2 @73,300,000 | ap3 @73,700,000 | ap4 @75,100,000
  // h2 f32 @80,500,000 | h3 f32 @89,000,000 | h4 f32 @90,500,000 | y1 @90,600,000
  // cnt @90,700,000 (192 B) | lists @90,701,024 (98,304 B) -> ends ~90.8 MB
  float* cube4 = (float*)(ws + 0);
  float* h1    = (float*)(ws + 32928000);
  u16*   ap1   = (u16*)(ws + 73200000);
  u16*   ap2   = (u16*)(ws + 73300000);
  u16*   ap3   = (u16*)(ws + 73700000);
  u16*   ap4   = (u16*)(ws + 75100000);
  float* h2    = (float*)(ws + 80500000);
  float* h3    = (float*)(ws + 89000000);
  float* h4    = (float*)(ws + 90500000);
  float* y1    = (float*)(ws + 90600000);
  int*   cnt   = (int*)(ws + 90700000);
  int*   lists = (int*)(ws + 90701024);

  k_pack_c1<<<(32 * 896 + 255) / 256, 256, 0, stream>>>(w1, ap1);
  k_pack_c32<<<(64 * 2592 + 255) / 256, 256, 0, stream>>>(w2, ap2, 32, 64);
  k_pack_c32<<<(128 * 5184 + 255) / 256, 256, 0, stream>>>(w3, ap3, 64, 128);
  k_pack_c32<<<(256 * 10368 + 255) / 256, 256, 0, stream>>>(w4, ap4, 128, 256);

  // atom extraction (once for all 8 batches)
  k_zero<<<1, 256, 0, stream>>>((float*)cnt, 12);  // 48 ints
  const int N4 = (BATCH * NEL * DIMV * DIMV * DIMV) / 4;
  k_scan<<<(N4 + 255) / 256, 256, 0, stream>>>(x, cnt, lists);

  for (int half = 0; half < 2; ++half) {
    int b0 = 4 * half;
    k_gather<<<dim3(DIMV, 4 * NEL), 256, 0, stream>>>(cnt, lists, sig, cube4, b0);
    k_conv_mfma<6, 32, 70, 16, 2, 1, 5>
        <<<dim3(34 * 34, 4), 128, 0, stream>>>(ap1, cube4, b1, h1, b0);
  }
  //            CINL COUT DIN CC  W  MR XT
  k_conv_mfma<32,  64, 34, 32, 4, 1, 2><<<dim3(16 * 16, 8), 256, 0, stream>>>(ap2, h1, b2, h2, 0);
  k_conv_mfma<64, 128, 16, 32, 8, 1, 1><<<dim3(7 * 7, 8),   512, 0, stream>>>(ap3, h2, b3, h3, 0);
  k_conv_mfma<128,256,  7, 32, 8, 2, 1><<<dim3(2 * 2, 8),   512, 0, stream>>>(ap4, h3, b4, h4, 0);

  k_fc1<<<1024, 64, 0, stream>>>(h4, fw1, fb1, y1);
  k_fc2<<<29, 64, 0, stream>>>(y1, fw2, fb2, (float*)d_out);
}